// Round 8
// baseline (269.783 us; speedup 1.0000x reference)
//
#include <hip/hip_runtime.h>
#include <hip/hip_bf16.h>
#include <cstdint>

// Problem constants (B=4, S=2048, D2=1024, DV=64, d_k=64)
#define S_LEN 2048
#define D2_   1024
#define DV_   64
#define NB_   4

typedef __bf16 bf16x8 __attribute__((ext_vector_type(8)));
typedef float  f32x4  __attribute__((ext_vector_type(4)));
typedef int    i32x4  __attribute__((ext_vector_type(4)));

// fp32 -> bf16 round-to-nearest-even
__device__ __forceinline__ unsigned short f2bf(float f) {
  union { float f; unsigned int u; } v; v.f = f;
  unsigned int r = v.u + 0x7fffu + ((v.u >> 16) & 1u);
  return (unsigned short)(r >> 16);
}

// async global->LDS, 16B per lane (global_load_lds_dwordx4)
__device__ __forceinline__ void async16(const unsigned short* g, unsigned short* l) {
  __builtin_amdgcn_global_load_lds(
      (__attribute__((address_space(1))) void*)g,
      (__attribute__((address_space(3))) void*)l,
      16, 0, 0);
}

// ---------------------------------------------------------------------------
// Kernel 1 (fused prep): per row r:
//   qn[r,:] = bf16( LN(q[r,:]) * 0.125 )      (1/sqrt(64) folded in)
//   kb[r,:] = bf16( k[r,:] )
//   blocks 0..3:  w2[d] = fc_w[d,:] . V       (rank-1 collapse of @fc_w.T)
//   blocks 0..31: zero rowsum[] (d_ws is poisoned 0xAA before every launch)
// ---------------------------------------------------------------------------
__global__ void __launch_bounds__(256) prep_kernel(
    const float* __restrict__ q, const float* __restrict__ k,
    const float* __restrict__ gam, const float* __restrict__ bet,
    const float* __restrict__ V, const float* __restrict__ fw,
    unsigned short* __restrict__ qn, unsigned short* __restrict__ kb,
    float* __restrict__ w2, float* __restrict__ rowsum) {
  const int row = blockIdx.x;
  const int t = threadIdx.x;

  if (row < 32) rowsum[row * 256 + t] = 0.0f;   // 8192 floats total

  // ---- LN(q) ----
  const float4 x = ((const float4*)(q + (size_t)row * D2_))[t];
  float s  = x.x + x.y + x.z + x.w;
  float ss = x.x * x.x + x.y * x.y + x.z * x.z + x.w * x.w;
  #pragma unroll
  for (int o = 32; o > 0; o >>= 1) { s += __shfl_down(s, o); ss += __shfl_down(ss, o); }
  __shared__ float red[8];
  if ((t & 63) == 0) { red[t >> 6] = s; red[(t >> 6) + 4] = ss; }
  __syncthreads();
  const float tot  = red[0] + red[1] + red[2] + red[3];
  const float tots = red[4] + red[5] + red[6] + red[7];
  const float mu  = tot * (1.0f / D2_);
  const float var = tots * (1.0f / D2_) - mu * mu;
  const float rs  = rsqrtf(var + 1e-6f) * 0.125f;
  const float4 gv = ((const float4*)gam)[t];
  const float4 bv = ((const float4*)bet)[t];
  ushort4 o4;
  o4.x = f2bf((x.x - mu) * rs * gv.x + 0.125f * bv.x);
  o4.y = f2bf((x.y - mu) * rs * gv.y + 0.125f * bv.y);
  o4.z = f2bf((x.z - mu) * rs * gv.z + 0.125f * bv.z);
  o4.w = f2bf((x.w - mu) * rs * gv.w + 0.125f * bv.w);
  ((ushort4*)(qn + (size_t)row * D2_))[t] = o4;

  // ---- cast k row ----
  const float4 kx = ((const float4*)(k + (size_t)row * D2_))[t];
  ushort4 k4;
  k4.x = f2bf(kx.x); k4.y = f2bf(kx.y); k4.z = f2bf(kx.z); k4.w = f2bf(kx.w);
  ((ushort4*)(kb + (size_t)row * D2_))[t] = k4;

  // ---- w2 (blocks 0..3) ----
  if (row < 4) {
    const int d = row * 256 + t;
    const float4* r  = (const float4*)(fw + (size_t)d * DV_);
    const float4* vv = (const float4*)V;
    float acc = 0.f;
    #pragma unroll
    for (int j = 0; j < 16; ++j) {
      const float4 a = r[j], b = vv[j];
      acc += a.x * b.x + a.y * b.y + a.z * b.z + a.w * b.w;
    }
    w2[d] = acc;
  }
}

// ---------------------------------------------------------------------------
// Kernel 2: attn = masked( qn @ kb^T );  rowsum += per-row sums.
// R13: counted-vmcnt double-buffer (T3/T4 proper).  R9's dbuf failed because
// __syncthreads() drains vmcnt(0) at every barrier (the documented ~20%
// structural stall; m99/m100 nulls).  The proven lever (m218: counted-vs-
// drain0 = +38-73%) is: raw s_barrier + asm s_waitcnt vmcnt(N), N>0 in the
// main loop -- next tile's DMA stays IN FLIGHT across the barrier.
//   prologue: STAGE tile0->buf0, tile1->buf1      (16 loads/wave outstanding)
//   iter kt (0..14): vmcnt(8)  = tile kt's 8 loads done, kt+1's 8 in flight
//                    s_barrier = every wave certified its own loads -> LDS ok
//                    compute(buf[kt&1])   (ds_read->MFMA, compiler lgkmcnt)
//                    s_barrier = all waves done READING buf[kt&1]
//                    STAGE tile kt+2 -> buf[kt&1]  (kt<14)
//   tail kt=15: vmcnt(0), barrier, compute(buf1).
// Safety: each wave waits its OWN vmcnt before the barrier, so after the
// barrier ALL waves' older loads are complete (HK pattern, m201 verified).
// Mask stays in the epilogue (R12: in-loop placement worth <=1us, and mask
// loads would corrupt the static vmcnt count).  Everything else = R11/R12:
// m97 wave shape (4 waves, 64x64/wave, acc[4][4]), 128^2 tile, BK=64,
// granule-XOR LDS layout (row r at 128B stride, granule s at (s^(r&7))*16B),
// XCD-chunked bijective swizzle, swapped MFMA operands (kb first).
// LDS 2 x 32 KiB = 64 KiB -> 2 blocks/CU (pipeline replaces TLP).
// ---------------------------------------------------------------------------
__global__ void __launch_bounds__(256, 2) attn_gemm_kernel(
    const unsigned short* __restrict__ qn,   // [B*S, D2] bf16
    const unsigned short* __restrict__ kb,   // [B*S, D2] bf16
    const int* __restrict__ mask,            // [B, S, S] int32
    float* __restrict__ attn,                // [B, S, S] f32
    float* __restrict__ rowsum) {            // [B*S] f32 (pre-zeroed)
  __shared__ __align__(16) unsigned short Asm_[2 * 8192];   // 2 bufs x 16 KiB
  __shared__ __align__(16) unsigned short Bsm_[2 * 8192];

  const int t = threadIdx.x;

  // XCD-chunked swizzle: XCD c owns contiguous work ids [c*128, (c+1)*128)
  // = 8 m-panels x all 16 n-panels (A panel reused 16x inside one L2).
  const int orig = blockIdx.x + 16 * (blockIdx.y + 16 * blockIdx.z);
  const int swz  = (orig & 7) * 128 + (orig >> 3);
  const int bn = (swz & 15) * 128;
  const int bm = ((swz >> 4) & 15) * 128;
  const int bt = swz >> 8;

  // staging base: thread t -> row (t>>3) of each 32-row quarter,
  // permuted granule (t&7)^(row&7)  (row&7 == (t>>3)&7 for all quarters)
  const int srow_ = t >> 3;                 // 0..31
  const int pg_   = (t & 7) ^ (srow_ & 7);
  const unsigned short* gA = qn + ((size_t)bt * S_LEN + bm + srow_) * D2_ + pg_ * 8;
  const unsigned short* gB = kb + ((size_t)bt * S_LEN + bn + srow_) * D2_ + pg_ * 8;
  unsigned short* lA = Asm_ + t * 8;
  unsigned short* lB = Bsm_ + t * 8;

  const int lane = t & 63;
  const int w  = t >> 6;                    // wave 0..3
  const int wm = (w >> 1) * 64;             // wave m offset (0/64)
  const int wn = (w & 1) * 64;              // wave n offset (0/64)
  const int lr = lane & 15;
  const int lg = lane >> 4;

  // stage one 64-wide K-tile (32 KiB total) into buffer `buf` (0 or 8192):
  // 4 row-quarters per matrix, 8 global_load_lds per thread (8/wave vmcnt).
  #define STAGE(buf, koff) do {                                     \
      _Pragma("unroll")                                             \
      for (int qq = 0; qq < 4; ++qq) {                              \
        async16(gA + (koff) + (size_t)qq * 32 * D2_, lA + (buf) + qq * 2048); \
        async16(gB + (koff) + (size_t)qq * 32 * D2_, lB + (buf) + qq * 2048); \
      }                                                             \
    } while (0)

  f32x4 acc[4][4] = {};           // [fm][fn]

  // compute one staged 64-K tile from LDS short-offset pl (0 or 8192)
  auto compute = [&](int pl) {
    #pragma unroll
    for (int ks = 0; ks < 2; ++ks) {
      // K-chunk ks needs granule ks*4+lg: slot ((ks*4+lg) ^ (row&7)), row&7==lr&7
      const int sl = ((ks << 2) + lg) ^ (lr & 7);
      bf16x8 af[4], bfv[4];
      #pragma unroll
      for (int f = 0; f < 4; ++f)
        af[f]  = *(const bf16x8*)(Asm_ + pl + (wm + f * 16 + lr) * 64 + sl * 8);
      #pragma unroll
      for (int f = 0; f < 4; ++f)
        bfv[f] = *(const bf16x8*)(Bsm_ + pl + (wn + f * 16 + lr) * 64 + sl * 8);
      #pragma unroll
      for (int fm = 0; fm < 4; ++fm)
        #pragma unroll
        for (int fn = 0; fn < 4; ++fn)
          acc[fm][fn] = __builtin_amdgcn_mfma_f32_16x16x32_bf16(
              bfv[fn], af[fm], acc[fm][fn], 0, 0, 0);   // swapped order
    }
  };

  // prologue: 2 tiles in flight (16 outstanding vmem/wave)
  STAGE(0, 0);
  STAGE(8192, 64);

  // main loop: counted vmcnt, no drain-to-0 until the tail.
  #pragma unroll 1
  for (int kt = 0; kt < 15; ++kt) {
    const int cur = (kt & 1) * 8192;
    asm volatile("s_waitcnt vmcnt(8)" ::: "memory");   // tile kt landed
    __builtin_amdgcn_s_barrier();                      // ...for ALL waves
    compute(cur);
    __builtin_amdgcn_s_barrier();                      // all reads of cur done
    if (kt < 14) STAGE(cur, (kt + 2) * 64);            // refill cur
  }
  // tail: tile 15 (only 8 loads outstanding)
  asm volatile("s_waitcnt vmcnt(0)" ::: "memory");
  __builtin_amdgcn_s_barrier();
  compute(8192);

  // epilogue: nontemporal mask loads (read-once 64 MB stream) + masked
  // stores + rowsum reduce.
  const int m_base = bm + wm + lr;
  const size_t rb0 = ((size_t)bt * S_LEN) * S_LEN;
  #pragma unroll
  for (int fm = 0; fm < 4; ++fm) {
    const int m = m_base + fm * 16;
    const size_t rowbase = rb0 + (size_t)m * S_LEN;
    float s = 0.f;
    #pragma unroll
    for (int fn = 0; fn < 4; ++fn) {
      const int n0 = bn + wn + fn * 16 + lg * 4;
      const i32x4 mk = __builtin_nontemporal_load((const i32x4*)(mask + rowbase + n0));
      f32x4 v;
      v[0] = mk[0] ? 0.0f : acc[fm][fn][0];
      v[1] = mk[1] ? 0.0f : acc[fm][fn][1];
      v[2] = mk[2] ? 0.0f : acc[fm][fn][2];
      v[3] = mk[3] ? 0.0f : acc[fm][fn][3];
      *(f32x4*)(attn + rowbase + n0) = v;
      s += v[0] + v[1] + v[2] + v[3];
    }
    // reduce across the 4 lg groups sharing this row
    s += __shfl_xor(s, 16);
    s += __shfl_xor(s, 32);
    if (lane < 16) atomicAdd(rowsum + (size_t)bt * S_LEN + m, s);
  }
  #undef STAGE
}

// ---------------------------------------------------------------------------
// Kernel 3: out[row,:] = rowsum[row] * w2[:] + fc_b[:] + q[row,:]
// (never touches attn).  Overwrites the out-region that held qn/kb; reads
// nothing from it — safe under stream ordering.
// ---------------------------------------------------------------------------
__global__ void __launch_bounds__(256) out_kernel(
    const float* __restrict__ rowsum, const float* __restrict__ q,
    const float* __restrict__ w2, const float* __restrict__ fcb,
    float* __restrict__ out) {
  const int row = blockIdx.x;
  const int t = threadIdx.x;
  const float rs = rowsum[row];
  const float4 wv = ((const float4*)w2)[t];
  const float4 bv = ((const float4*)fcb)[t];
  const float4 qv = ((const float4*)(q + (size_t)row * D2_))[t];
  float4 o4;
  o4.x = rs * wv.x + bv.x + qv.x;
  o4.y = rs * wv.y + bv.y + qv.y;
  o4.z = rs * wv.z + bv.z + qv.z;
  o4.w = rs * wv.w + bv.w + qv.w;
  ((float4*)(out + (size_t)row * D2_))[t] = o4;
}

// ---------------------------------------------------------------------------
extern "C" void kernel_launch(void* const* d_in, const int* in_sizes, int n_in,
                              void* d_out, int out_size, void* d_ws, size_t ws_size,
                              hipStream_t stream) {
  (void)in_sizes; (void)n_in; (void)out_size; (void)ws_size;
  const float* q    = (const float*)d_in[0];
  const float* k    = (const float*)d_in[1];
  /* d_in[2] == v: provably unused by the reference computation */
  const int*   mask = (const int*)d_in[3];
  const float* V    = (const float*)d_in[4];
  const float* fw   = (const float*)d_in[5];
  const float* fcb  = (const float*)d_in[6];
  const float* lg   = (const float*)d_in[7];
  const float* lb   = (const float*)d_in[8];

  float* out  = (float*)d_out;                          // [B,S,D2]  32 MiB
  float* attn = out + (size_t)NB_ * S_LEN * D2_;        // [B,S,S]   64 MiB

  // qn/kb live INSIDE the out-region (exactly 32 MiB), dead until out_kernel
  // overwrites it last.  d_ws: w2 (4 KiB) + rowsum (32 KiB).
  unsigned short* qn = (unsigned short*)out;                     // 16 MiB
  unsigned short* kb = qn + (size_t)NB_ * S_LEN * D2_;           // 16 MiB
  float* w2     = (float*)d_ws;                                  // 1024 f
  float* rowsum = w2 + D2_;                                      // 8192 f

  prep_kernel<<<NB_ * S_LEN, 256, 0, stream>>>(q, k, lg, lb, V, fw, qn, kb, w2, rowsum);
  attn_gemm_kernel<<<dim3(S_LEN / 128, S_LEN / 128, NB_), 256, 0, stream>>>(qn, kb, mask, attn, rowsum);
  out_kernel<<<NB_ * S_LEN, 256, 0, stream>>>(rowsum, q, w2, fcb, out);
}

// Round 11
// 266.335 us; speedup vs baseline: 1.0129x; 1.0129x over previous
//
#include <hip/hip_runtime.h>
#include <hip/hip_bf16.h>
#include <cstdint>

// Problem constants (B=4, S=2048, D2=1024, DV=64, d_k=64)
#define S_LEN 2048
#define D2_   1024
#define DV_   64
#define NB_   4

typedef __bf16 bf16x8 __attribute__((ext_vector_type(8)));
typedef float  f32x4  __attribute__((ext_vector_type(4)));
typedef int    i32x4  __attribute__((ext_vector_type(4)));

// fp32 -> bf16 round-to-nearest-even
__device__ __forceinline__ unsigned short f2bf(float f) {
  union { float f; unsigned int u; } v; v.f = f;
  unsigned int r = v.u + 0x7fffu + ((v.u >> 16) & 1u);
  return (unsigned short)(r >> 16);
}

// async global->LDS, 16B per lane (global_load_lds_dwordx4)
__device__ __forceinline__ void async16(const unsigned short* g, unsigned short* l) {
  __builtin_amdgcn_global_load_lds(
      (__attribute__((address_space(1))) void*)g,
      (__attribute__((address_space(3))) void*)l,
      16, 0, 0);
}

// ---------------------------------------------------------------------------
// Kernel 1 (fused prep): unchanged (proven).
// ---------------------------------------------------------------------------
__global__ void __launch_bounds__(256) prep_kernel(
    const float* __restrict__ q, const float* __restrict__ k,
    const float* __restrict__ gam, const float* __restrict__ bet,
    const float* __restrict__ V, const float* __restrict__ fw,
    unsigned short* __restrict__ qn, unsigned short* __restrict__ kb,
    float* __restrict__ w2, float* __restrict__ rowsum) {
  const int row = blockIdx.x;
  const int t = threadIdx.x;

  if (row < 32) rowsum[row * 256 + t] = 0.0f;   // 8192 floats total

  const float4 x = ((const float4*)(q + (size_t)row * D2_))[t];
  float s  = x.x + x.y + x.z + x.w;
  float ss = x.x * x.x + x.y * x.y + x.z * x.z + x.w * x.w;
  #pragma unroll
  for (int o = 32; o > 0; o >>= 1) { s += __shfl_down(s, o); ss += __shfl_down(ss, o); }
  __shared__ float red[8];
  if ((t & 63) == 0) { red[t >> 6] = s; red[(t >> 6) + 4] = ss; }
  __syncthreads();
  const float tot  = red[0] + red[1] + red[2] + red[3];
  const float tots = red[4] + red[5] + red[6] + red[7];
  const float mu  = tot * (1.0f / D2_);
  const float var = tots * (1.0f / D2_) - mu * mu;
  const float rs  = rsqrtf(var + 1e-6f) * 0.125f;
  const float4 gv = ((const float4*)gam)[t];
  const float4 bv = ((const float4*)bet)[t];
  ushort4 o4;
  o4.x = f2bf((x.x - mu) * rs * gv.x + 0.125f * bv.x);
  o4.y = f2bf((x.y - mu) * rs * gv.y + 0.125f * bv.y);
  o4.z = f2bf((x.z - mu) * rs * gv.z + 0.125f * bv.z);
  o4.w = f2bf((x.w - mu) * rs * gv.w + 0.125f * bv.w);
  ((ushort4*)(qn + (size_t)row * D2_))[t] = o4;

  const float4 kx = ((const float4*)(k + (size_t)row * D2_))[t];
  ushort4 k4;
  k4.x = f2bf(kx.x); k4.y = f2bf(kx.y); k4.z = f2bf(kx.z); k4.w = f2bf(kx.w);
  ((ushort4*)(kb + (size_t)row * D2_))[t] = k4;

  if (row < 4) {
    const int d = row * 256 + t;
    const float4* r  = (const float4*)(fw + (size_t)d * DV_);
    const float4* vv = (const float4*)V;
    float acc = 0.f;
    #pragma unroll
    for (int j = 0; j < 16; ++j) {
      const float4 a = r[j], b = vv[j];
      acc += a.x * b.x + a.y * b.y + a.z * b.z + a.w * b.w;
    }
    w2[d] = acc;
  }
}

// ---------------------------------------------------------------------------
// Kernel 2 R14: 256^2 tile, 4-phase-per-K-tile interleaved schedule.
// R13 post-mortem: counted-vmcnt at 128^2 = regression (m232 quadrant);
// 128^2 K-loop is AT its structure ceiling (~840-900 TF).  This is the 256^2
// port (m198/m201 lineage) with a conservative, provably-race-free wait
// chain:
//   512 thr / 8 waves (2Mx4N), per-wave 128x64 out (acc[8][4]), BK=64.
//   LDS: A,B each 2 x 16384 shorts (2 bufs) = 128 KiB total, 1 block/CU.
//   Iteration (2 K-tiles; buf0 = even tile, buf1 = odd):
//     group A: 4 phases, each { stage 2-of-8 gload_lds of tile kt+1 -> buf1;
//              ds_read subtile from buf0; setprio(1); 16 MFMA; setprio(0) }
//     boundary: s_waitcnt vmcnt(0) + s_barrier  (cheap: newest load was
//              issued one full MFMA phase (~1200cy >> L2 latency) earlier)
//     group B: same computing buf1, staging kt+2 -> buf0; boundary.
//   Invariants: a buffer is DMA-written only between the barrier that ends
//   its last reads and the barrier that precedes its next reads; vmcnt(0) at
//   each boundary certifies every wave's own loads, barrier extends to all.
//   asm("" ::: "memory") after each barrier pins ds_reads below it.
// Proven pieces carried over unchanged: granule-XOR LDS layout (row r at
// 128B stride, granule s at (s^(r&7))*16B -> 2-way-free banks; staging
// thread t -> row t>>3, global granule (t&7)^(row&7)); XCD-chunked bijective
// swizzle (256 wgs); swapped MFMA operands (kb first): m = wm+fm*16+lr,
// n = wn+fn*16+lg*4+j; R11 epilogue (nt mask loads) extended to 8x4.
// ---------------------------------------------------------------------------
__global__ void __launch_bounds__(512, 2) attn_gemm_kernel(
    const unsigned short* __restrict__ qn,   // [B*S, D2] bf16
    const unsigned short* __restrict__ kb,   // [B*S, D2] bf16
    const int* __restrict__ mask,            // [B, S, S] int32
    float* __restrict__ attn,                // [B, S, S] f32
    float* __restrict__ rowsum) {            // [B*S] f32 (pre-zeroed)
  __shared__ __align__(16) unsigned short Asm_[2 * 16384];   // 64 KiB
  __shared__ __align__(16) unsigned short Bsm_[2 * 16384];   // 64 KiB

  const int t = threadIdx.x;

  // XCD-chunked swizzle over 256 workgroups (256 % 8 == 0 -> bijective).
  const int orig = blockIdx.x + 8 * (blockIdx.y + 8 * blockIdx.z);
  const int swz  = (orig & 7) * 32 + (orig >> 3);
  const int bn = (swz & 7) * 256;
  const int bm = ((swz >> 3) & 7) * 256;
  const int bt = swz >> 6;

  // staging: thread t -> row t>>3 (0..63) of each 64-row sweep,
  // permuted granule (t&7)^(row&7)
  const int srow_ = t >> 3;
  const int pg_   = (t & 7) ^ (srow_ & 7);
  const unsigned short* gA = qn + ((size_t)bt * S_LEN + bm + srow_) * D2_ + pg_ * 8;
  const unsigned short* gB = kb + ((size_t)bt * S_LEN + bn + srow_) * D2_ + pg_ * 8;
  unsigned short* lA = Asm_ + t * 8;
  unsigned short* lB = Bsm_ + t * 8;

  const int lane = t & 63;
  const int w  = t >> 6;                    // wave 0..7
  const int wm = (w >> 2) * 128;            // wave m offset (0/128)
  const int wn = (w & 3) * 64;              // wave n offset (0/64/128/192)
  const int lr = lane & 15;
  const int lg = lane >> 4;

  // stage sweeps s0, s0+1 (64 rows x 64 K each) of matrix mat of tile dtile
  auto stage2 = [&](int dstbuf, int dtile, int mat, int s0) {
    const unsigned short* g = mat ? gB : gA;
    unsigned short* l = mat ? lB : lA;
    #pragma unroll
    for (int s = s0; s < s0 + 2; ++s)
      async16(g + (size_t)dtile * 64 + (size_t)s * 64 * D2_, l + dstbuf + s * 4096);
  };

  f32x4 acc[8][4] = {};           // [fm][fn]

  // compute one K-tile from LDS offset src; stage tile dtile into dst
  // (4 phases: ph0 A-sweeps01, ph1 A-sweeps23, ph2 B-sweeps01, ph3 B-sweeps23)
  auto group = [&](int src, int dst, int dtile, bool do_stage) {
    #pragma unroll
    for (int ks = 0; ks < 2; ++ks) {
      const int sl = ((ks << 2) + lg) ^ (lr & 7);
      bf16x8 bfv[4];
      #pragma unroll
      for (int mg = 0; mg < 2; ++mg) {
        const int ph = ks * 2 + mg;
        if (do_stage) stage2(dst, dtile, ph >> 1, (ph & 1) * 2);
        if (mg == 0) {
          #pragma unroll
          for (int f = 0; f < 4; ++f)
            bfv[f] = *(const bf16x8*)(Bsm_ + src + (wn + f * 16 + lr) * 64 + sl * 8);
        }
        bf16x8 af[4];
        #pragma unroll
        for (int f = 0; f < 4; ++f)
          af[f] = *(const bf16x8*)(Asm_ + src + (wm + (mg * 4 + f) * 16 + lr) * 64 + sl * 8);
        __builtin_amdgcn_s_setprio(1);
        #pragma unroll
        for (int f = 0; f < 4; ++f)
          #pragma unroll
          for (int fn = 0; fn < 4; ++fn)
            acc[mg * 4 + f][fn] = __builtin_amdgcn_mfma_f32_16x16x32_bf16(
                bfv[fn], af[f], acc[mg * 4 + f][fn], 0, 0, 0);   // swapped order
        __builtin_amdgcn_s_setprio(0);
      }
    }
  };

  // prologue: tile 0 -> buf0 (8 loads/thread), full drain once.
  #pragma unroll
  for (int s = 0; s < 4; ++s) {
    async16(gA + (size_t)s * 64 * D2_, lA + s * 4096);
    async16(gB + (size_t)s * 64 * D2_, lB + s * 4096);
  }
  asm volatile("s_waitcnt vmcnt(0)" ::: "memory");
  __builtin_amdgcn_s_barrier();
  asm volatile("" ::: "memory");

  // 16 K-tiles, 2 per iteration.
  #pragma unroll 1
  for (int kt = 0; kt < 16; kt += 2) {
    group(0, 16384, kt + 1, true);          // compute kt (buf0), stage kt+1->buf1
    asm volatile("s_waitcnt vmcnt(0)" ::: "memory");
    __builtin_amdgcn_s_barrier();
    asm volatile("" ::: "memory");
    group(16384, 0, kt + 2, kt + 2 < 16);   // compute kt+1 (buf1), stage kt+2->buf0
    asm volatile("s_waitcnt vmcnt(0)" ::: "memory");
    __builtin_amdgcn_s_barrier();
    asm volatile("" ::: "memory");
  }

  // epilogue: nt mask loads (read-once 64 MB) + masked stores + rowsum.
  const int m_base = bm + wm + lr;
  const size_t rb0 = ((size_t)bt * S_LEN) * S_LEN;
  #pragma unroll
  for (int fm = 0; fm < 8; ++fm) {
    const int m = m_base + fm * 16;
    const size_t rowbase = rb0 + (size_t)m * S_LEN;
    float s = 0.f;
    #pragma unroll
    for (int fn = 0; fn < 4; ++fn) {
      const int n0 = bn + wn + fn * 16 + lg * 4;
      const i32x4 mk = __builtin_nontemporal_load((const i32x4*)(mask + rowbase + n0));
      f32x4 v;
      v[0] = mk[0] ? 0.0f : acc[fm][fn][0];
      v[1] = mk[1] ? 0.0f : acc[fm][fn][1];
      v[2] = mk[2] ? 0.0f : acc[fm][fn][2];
      v[3] = mk[3] ? 0.0f : acc[fm][fn][3];
      *(f32x4*)(attn + rowbase + n0) = v;
      s += v[0] + v[1] + v[2] + v[3];
    }
    // reduce across the 4 lg groups sharing this row
    s += __shfl_xor(s, 16);
    s += __shfl_xor(s, 32);
    if (lane < 16) atomicAdd(rowsum + (size_t)bt * S_LEN + m, s);
  }
}

// ---------------------------------------------------------------------------
// Kernel 3: out[row,:] = rowsum[row] * w2[:] + fc_b[:] + q[row,:]  (unchanged)
// ---------------------------------------------------------------------------
__global__ void __launch_bounds__(256) out_kernel(
    const float* __restrict__ rowsum, const float* __restrict__ q,
    const float* __restrict__ w2, const float* __restrict__ fcb,
    float* __restrict__ out) {
  const int row = blockIdx.x;
  const int t = threadIdx.x;
  const float rs = rowsum[row];
  const float4 wv = ((const float4*)w2)[t];
  const float4 bv = ((const float4*)fcb)[t];
  const float4 qv = ((const float4*)(q + (size_t)row * D2_))[t];
  float4 o4;
  o4.x = rs * wv.x + bv.x + qv.x;
  o4.y = rs * wv.y + bv.y + qv.y;
  o4.z = rs * wv.z + bv.z + qv.z;
  o4.w = rs * wv.w + bv.w + qv.w;
  ((float4*)(out + (size_t)row * D2_))[t] = o4;
}

// ---------------------------------------------------------------------------
extern "C" void kernel_launch(void* const* d_in, const int* in_sizes, int n_in,
                              void* d_out, int out_size, void* d_ws, size_t ws_size,
                              hipStream_t stream) {
  (void)in_sizes; (void)n_in; (void)out_size; (void)ws_size;
  const float* q    = (const float*)d_in[0];
  const float* k    = (const float*)d_in[1];
  /* d_in[2] == v: provably unused by the reference computation */
  const int*   mask = (const int*)d_in[3];
  const float* V    = (const float*)d_in[4];
  const float* fw   = (const float*)d_in[5];
  const float* fcb  = (const float*)d_in[6];
  const float* lg   = (const float*)d_in[7];
  const float* lb   = (const float*)d_in[8];

  float* out  = (float*)d_out;                          // [B,S,D2]  32 MiB
  float* attn = out + (size_t)NB_ * S_LEN * D2_;        // [B,S,S]   64 MiB

  // qn/kb live INSIDE the out-region (exactly 32 MiB), dead until out_kernel
  // overwrites it last.  d_ws: w2 (4 KiB) + rowsum (32 KiB).
  unsigned short* qn = (unsigned short*)out;                     // 16 MiB
  unsigned short* kb = qn + (size_t)NB_ * S_LEN * D2_;           // 16 MiB
  float* w2     = (float*)d_ws;                                  // 1024 f
  float* rowsum = w2 + D2_;                                      // 8192 f

  prep_kernel<<<NB_ * S_LEN, 256, 0, stream>>>(q, k, lg, lb, V, fw, qn, kb, w2, rowsum);
  attn_gemm_kernel<<<dim3(S_LEN / 256, S_LEN / 256, NB_), 512, 0, stream>>>(qn, kb, mask, attn, rowsum);
  out_kernel<<<NB_ * S_LEN, 256, 0, stream>>>(rowsum, q, w2, fcb, out);
}